// Round 12
// baseline (172.741 us; speedup 1.0000x reference)
//
#include <hip/hip_runtime.h>
#include <hip/hip_bf16.h>
#include <stdint.h>

typedef __attribute__((ext_vector_type(8))) short s8v;
typedef __attribute__((ext_vector_type(4))) float f4v;

#define T_TOT 8
#define NSP 32768   // T*H*W
#define K_TOT 1024
#define M_TOT 1024

__device__ __forceinline__ unsigned short f2bf(float f) {
  unsigned int u = __float_as_uint(f);
  u += 0x7FFF + ((u >> 16) & 1);   // round-to-nearest-even
  return (unsigned short)(u >> 16);
}

// ---------------------------------------------------------------------------
// Kernel 1 (unchanged, ~35us, at its BW floor): depthwise 3x3x3.
// ---------------------------------------------------------------------------
__global__ __launch_bounds__(256) void dw_kernel(const float* __restrict__ X,
                                                 const float* __restrict__ DW,
                                                 unsigned short* __restrict__ Yn) {
  __shared__ float xin[8 * 18 * 64];         // 36 KB  [t][hr][w]
  const int tid = threadIdx.x;
  const int hb  = blockIdx.x;                // 0..3
  const int c   = blockIdx.y;                // 0..1023
  const int h0  = hb * 16;

  float kw[27];
#pragma unroll
  for (int j = 0; j < 27; ++j) kw[j] = DW[j];

  const float* Xc = X + (size_t)c * NSP;

#pragma unroll
  for (int i = 0; i < 9; ++i) {
    const int f  = tid + i * 256;
    const int r  = f >> 4;
    const int wq = (f & 15) * 4;
    const int t  = r / 18;
    const int hr = r - t * 18;
    const int hg = h0 - 1 + hr;
    const int hc = min(max(hg, 0), 63);
    float4 v = *(const float4*)(Xc + (t * 64 + hc) * 64 + wq);
    if (hg != hc) v = (float4){0.f, 0.f, 0.f, 0.f};
    *(float4*)&xin[r * 64 + wq] = v;
  }
  __syncthreads();

  const int w  = tid & 63;
  const int hq = tid >> 6;
  const int wl = (w == 0)  ? w : w - 1;
  const int wr = (w == 63) ? w : w + 1;
  const float* bC = &xin[(hq * 4) * 64 + w];
  const float* bL = &xin[(hq * 4) * 64 + wl];
  const float* bR = &xin[(hq * 4) * 64 + wr];
  unsigned short* Yb = Yn + (size_t)c * NSP + (h0 + hq * 4) * 64 + w;

  float a0[4], a1[4], a2[4];
#pragma unroll
  for (int j = 0; j < 4; ++j) { a0[j] = 0.f; a1[j] = 0.f; a2[j] = 0.f; }

#pragma unroll
  for (int tp = 0; tp < 8; ++tp) {
    float v[6][3];
#pragma unroll
    for (int rr = 0; rr < 6; ++rr) {
      const int off = (tp * 18 + rr) * 64;
      float xc = bC[off];
      float xl = bL[off];
      float xr = bR[off];
      if (w == 0)  xl = 0.f;
      if (w == 63) xr = 0.f;
      v[rr][0] = xl; v[rr][1] = xc; v[rr][2] = xr;
    }
#pragma unroll
    for (int j = 0; j < 4; ++j)
#pragma unroll
      for (int kh = 0; kh < 3; ++kh)
#pragma unroll
        for (int kd = 0; kd < 3; ++kd) {
          const float xv = v[j + kh][kd];
          if (tp >= 1) a0[j] += kw[(2 * 3 + kh) * 3 + kd] * xv;
          a1[j] += kw[(1 * 3 + kh) * 3 + kd] * xv;
          if (tp <= 6) a2[j] += kw[(0 * 3 + kh) * 3 + kd] * xv;
        }
    if (tp >= 1) {
      unsigned short* yp = Yb + (size_t)(tp - 1) * 4096;
#pragma unroll
      for (int j = 0; j < 4; ++j) yp[j * 64] = f2bf(a0[j]);
    }
#pragma unroll
    for (int j = 0; j < 4; ++j) { a0[j] = a1[j]; a1[j] = a2[j]; a2[j] = 0.f; }
  }
  {
    unsigned short* yp = Yb + (size_t)7 * 4096;
#pragma unroll
    for (int j = 0; j < 4; ++j) yp[j * 64] = f2bf(a0[j]);
  }
}

// ---------------------------------------------------------------------------
// Kernel 2: pointwise weight fp32 -> bf16
// ---------------------------------------------------------------------------
__global__ __launch_bounds__(256) void castw_kernel(const float* __restrict__ Wf,
                                                    unsigned short* __restrict__ Wb) {
  const int i = (blockIdx.x * 256 + threadIdx.x) * 4;
  float4 v = *(const float4*)&Wf[i];
  ushort4 o;
  o.x = f2bf(v.x); o.y = f2bf(v.y); o.z = f2bf(v.z); o.w = f2bf(v.w);
  *(ushort4*)&Wb[i] = o;
}

// ---------------------------------------------------------------------------
// Kernel 3 (v8): C = A[M][K] * Y, with B consumed DIRECTLY from Yn[k][n]
// (tr_kernel deleted).  BM=BN=256, BK=64, 512 thr, 8 waves 2Mx4N,
// wave-tile 128x64, acc[8][4].  LDS 128KB = 2 buf x {Akk0,Akk1,Bkk0,Bkk1}
// x 16KB, all [256][32] with the proven XOR swizzle.
// A-path: global_load_lds with pre-swizzled source (unchanged, 0 conflicts).
// B-path: per thread per tile, 8x uint2 loads from Yn (8 k-rows x 4 n,
// full-64B-line coalesced), in-register 8x4 bf16 transpose, 4x ds_write_b128
// at swizzled addr chunkphys = chunk ^ ((row>>1)&3) == the read swizzle
// (both-sides by construction).
// Schedule: v7 4-phase skeleton; B loads t+1 issue in P0 (compiler auto-
// waits reg deps), transpose+write in P2 (nx-B last read >=3 barriers
// earlier), vmcnt(0)+lgkmcnt(0) before P3's barrier.
// ---------------------------------------------------------------------------
__device__ __forceinline__ unsigned pk16(unsigned a, unsigned b) {
  return (a & 0xFFFFu) | ((b & 0xFFFFu) << 16);
}

__global__ __launch_bounds__(512, 2) void gemm8_kernel(const unsigned short* __restrict__ A,
                                                       const unsigned short* __restrict__ Yn,
                                                       float* __restrict__ C) {
  __shared__ char smem[131072];              // 2 x {A0,A1,B0,B1} x 16KB
  const int tid  = threadIdx.x;
  const int lane = tid & 63;
  const int wid  = tid >> 6;
  const int wm   = wid >> 2, wn = wid & 3;   // 2 x 4 wave grid

  // bijective XCD remap: 512 wgs, 64 per XCD; bm fastest.
  const int wg = (int)blockIdx.x;
  const int lg = (wg & 7) * 64 + (wg >> 3);
  const int bm = lg & 3;                     // 0..3   (M/256)
  const int bn = lg >> 2;                    // 0..127 (N/256)

  f4v acc[8][4];
#pragma unroll
  for (int i = 0; i < 8; ++i)
#pragma unroll
    for (int j = 0; j < 4; ++j) acc[i][j] = (f4v){0.f, 0.f, 0.f, 0.f};

  // ---- A staging (unchanged, proven): global_load_lds, pre-swizzled k ----
  const int r  = tid >> 2;                                   // 0..127
  const int kb = (((tid & 3) ^ ((tid >> 3) & 3)) * 8);       // pre-swizzled k
  const unsigned short* ga = A + (size_t)(bm * 256 + r) * K_TOT + kb;
  const int stg = wid * 1024;

#define STAGE_A(nb, tt, kk)                                                   \
  do {                                                                        \
    const int ko = (tt) * 64 + (kk) * 32;                                     \
    char* ab = smem + (nb) + (kk) * 16384 + stg;                              \
    __builtin_amdgcn_global_load_lds(                                         \
        (const __attribute__((address_space(1))) void*)(uintptr_t)(ga + ko),  \
        (__attribute__((address_space(3))) void*)(uintptr_t)ab, 16, 0, 0);    \
    __builtin_amdgcn_global_load_lds(                                         \
        (const __attribute__((address_space(1))) void*)(uintptr_t)(ga + 128 * K_TOT + ko), \
        (__attribute__((address_space(3))) void*)(uintptr_t)(ab + 8192), 16, 0, 0); \
  } while (0)

  // ---- B staging: reg transpose from Yn ----
  const int kq8 = tid & 7;                   // k-group of 8: k = kq8*8 + j
  const int n4  = tid >> 3;                  // 0..63: n = n4*4 + e
  const unsigned short* gBth = Yn + (size_t)(kq8 * 8) * NSP + bn * 256 + n4 * 4;
  const int bkk   = kq8 >> 2;                // B region (kk half)
  const int bchk  = kq8 & 3;                 // logical 16B chunk in row
  // write byte offsets for e=0..3 (row = n4*4+e), swizzled like the reads
  int woff[4];
#pragma unroll
  for (int e = 0; e < 4; ++e) {
    const int row = n4 * 4 + e;
    woff[e] = 32768 + bkk * 16384 + row * 64 + ((bchk ^ ((row >> 1) & 3)) * 16);
  }

#define LOAD_B(Lv, tt)                                                        \
  do {                                                                        \
    const unsigned short* gb_ = gBth + (size_t)(tt) * 64 * NSP;               \
    _Pragma("unroll")                                                         \
    for (int j = 0; j < 8; ++j)                                               \
      Lv[j] = *(const uint2*)(gb_ + (size_t)j * NSP);                         \
  } while (0)

#define WRITE_B(Lv, nb)                                                       \
  do {                                                                        \
    _Pragma("unroll")                                                         \
    for (int e = 0; e < 4; ++e) {                                             \
      unsigned le[8];                                                         \
      _Pragma("unroll")                                                       \
      for (int j = 0; j < 8; ++j) {                                           \
        const unsigned s_ = (e < 2) ? Lv[j].x : Lv[j].y;                      \
        le[j] = (e & 1) ? (s_ >> 16) : (s_ & 0xFFFFu);                        \
      }                                                                       \
      uint4 wv_;                                                              \
      wv_.x = pk16(le[0], le[1]); wv_.y = pk16(le[2], le[3]);                 \
      wv_.z = pk16(le[4], le[5]); wv_.w = pk16(le[6], le[7]);                 \
      *(uint4*)(smem + (nb) + woff[e]) = wv_;                                 \
    }                                                                         \
  } while (0)

  const int cph  = ((lane >> 4) ^ ((lane >> 1) & 3)) * 8;    // swizzled col
  const int arow = wm * 128 + (lane & 15);
  const int brow = wn * 64  + (lane & 15);

#define MFMA16(mbase)                                                         \
  do {                                                                        \
    __builtin_amdgcn_s_setprio(1);                                            \
    _Pragma("unroll")                                                         \
    for (int mf = 0; mf < 4; ++mf)                                            \
      _Pragma("unroll")                                                       \
      for (int nf = 0; nf < 4; ++nf)                                          \
        acc[(mbase) + mf][nf] = __builtin_amdgcn_mfma_f32_16x16x32_bf16(      \
            av[mf], bv[nf], acc[(mbase) + mf][nf], 0, 0, 0);                  \
    __builtin_amdgcn_s_setprio(0);                                            \
  } while (0)

  // ---- prologue: tile 0 into buffer 0 ----
  {
    STAGE_A(0, 0, 0);
    STAGE_A(0, 0, 1);
    uint2 L[8];
    LOAD_B(L, 0);
    asm volatile("s_waitcnt vmcnt(0)" ::: "memory");
    WRITE_B(L, 0);
    asm volatile("s_waitcnt lgkmcnt(0)" ::: "memory");
    __builtin_amdgcn_s_barrier();
  }

  for (int t = 0; t < 15; ++t) {
    const int cu = (t & 1) << 16;
    const int nx = cu ^ 65536;
    const unsigned short* Ac = (const unsigned short*)(smem + cu);
    const unsigned short* Bc = (const unsigned short*)(smem + cu + 32768);
    s8v av[4], bv[4];
    uint2 L[8];

    // P0: reads kk0 (bv + av m0-3) | STAGE_A t+1 kk0 | B loads t+1 | barrier | MFMA
#pragma unroll
    for (int nf = 0; nf < 4; ++nf)
      bv[nf] = *(const s8v*)&Bc[(brow + nf * 16) * 32 + cph];
#pragma unroll
    for (int mf = 0; mf < 4; ++mf)
      av[mf] = *(const s8v*)&Ac[(arow + mf * 16) * 32 + cph];
    STAGE_A(nx, t + 1, 0);
    LOAD_B(L, t + 1);
    __builtin_amdgcn_s_barrier();
    MFMA16(0);

    // P1: reads av m4-7 kk0 | STAGE_A t+1 kk1 | barrier | MFMA
#pragma unroll
    for (int mf = 0; mf < 4; ++mf)
      av[mf] = *(const s8v*)&Ac[(arow + (mf + 4) * 16) * 32 + cph];
    STAGE_A(nx, t + 1, 1);
    __builtin_amdgcn_s_barrier();
    MFMA16(4);

    // P2: reads kk1 (bv + av m0-3) | transpose+write B t+1 -> nx | barrier | MFMA
#pragma unroll
    for (int nf = 0; nf < 4; ++nf)
      bv[nf] = *(const s8v*)&Bc[8192 + (brow + nf * 16) * 32 + cph];
#pragma unroll
    for (int mf = 0; mf < 4; ++mf)
      av[mf] = *(const s8v*)&Ac[8192 + (arow + mf * 16) * 32 + cph];
    WRITE_B(L, nx);                          // compiler waits B-load reg deps
    __builtin_amdgcn_s_barrier();
    MFMA16(0);

    // P3: reads av m4-7 kk1 | drain A-gloads + write-visibility | barrier | MFMA
#pragma unroll
    for (int mf = 0; mf < 4; ++mf)
      av[mf] = *(const s8v*)&Ac[8192 + (arow + (mf + 4) * 16) * 32 + cph];
    asm volatile("s_waitcnt vmcnt(0) lgkmcnt(0)" ::: "memory");
    __builtin_amdgcn_s_barrier();
    MFMA16(4);
  }

  // ---- tail: tile 15 (buffer 1), nothing to stage ----
  {
    const unsigned short* Ac = (const unsigned short*)(smem + 65536);
    const unsigned short* Bc = (const unsigned short*)(smem + 65536 + 32768);
    s8v av[4], bv[4];
#pragma unroll
    for (int nf = 0; nf < 4; ++nf)
      bv[nf] = *(const s8v*)&Bc[(brow + nf * 16) * 32 + cph];
#pragma unroll
    for (int mf = 0; mf < 4; ++mf)
      av[mf] = *(const s8v*)&Ac[(arow + mf * 16) * 32 + cph];
    __builtin_amdgcn_s_barrier();
    MFMA16(0);
#pragma unroll
    for (int mf = 0; mf < 4; ++mf)
      av[mf] = *(const s8v*)&Ac[(arow + (mf + 4) * 16) * 32 + cph];
    __builtin_amdgcn_s_barrier();
    MFMA16(4);
#pragma unroll
    for (int nf = 0; nf < 4; ++nf)
      bv[nf] = *(const s8v*)&Bc[8192 + (brow + nf * 16) * 32 + cph];
#pragma unroll
    for (int mf = 0; mf < 4; ++mf)
      av[mf] = *(const s8v*)&Ac[8192 + (arow + mf * 16) * 32 + cph];
    __builtin_amdgcn_s_barrier();
    MFMA16(0);
#pragma unroll
    for (int mf = 0; mf < 4; ++mf)
      av[mf] = *(const s8v*)&Ac[8192 + (arow + (mf + 4) * 16) * 32 + cph];
    MFMA16(4);
  }

#undef MFMA16
#undef WRITE_B
#undef LOAD_B
#undef STAGE_A

  const int rowq = (lane >> 4) * 4;
  const int colq = lane & 15;
#pragma unroll
  for (int mf = 0; mf < 8; ++mf) {
    const int row0 = bm * 256 + wm * 128 + mf * 16 + rowq;
#pragma unroll
    for (int nf = 0; nf < 4; ++nf) {
      const int col = bn * 256 + wn * 64 + nf * 16 + colq;
      float* cp = C + (size_t)row0 * NSP + col;
#pragma unroll
      for (int j = 0; j < 4; ++j) cp[(size_t)j * NSP] = acc[mf][nf][j];
    }
  }
}

// ---------------------------------------------------------------------------
extern "C" void kernel_launch(void* const* d_in, const int* in_sizes, int n_in,
                              void* d_out, int out_size, void* d_ws, size_t ws_size,
                              hipStream_t stream) {
  const float* feat = (const float*)d_in[0];
  const float* dw   = (const float*)d_in[1];
  const float* pw   = (const float*)d_in[2];
  float* out = (float*)d_out;

  unsigned short* Yn = (unsigned short*)d_ws;                 // [1024][32768] bf16, 64 MiB
  unsigned short* Wb = Yn + (size_t)K_TOT * NSP;              // [1024][1024] bf16, 2 MiB

  dw_kernel<<<dim3(4, 1024), dim3(256), 0, stream>>>(feat, dw, Yn);
  castw_kernel<<<dim3(1024), dim3(256), 0, stream>>>(pw, Wb);
  gemm8_kernel<<<dim3(512), dim3(512), 0, stream>>>(Wb, Yn, out);
}

// Round 13
// 159.043 us; speedup vs baseline: 1.0861x; 1.0861x over previous
//
#include <hip/hip_runtime.h>
#include <hip/hip_bf16.h>
#include <stdint.h>

typedef __attribute__((ext_vector_type(8))) short s8v;
typedef __attribute__((ext_vector_type(4))) float f4v;
typedef __attribute__((ext_vector_type(16))) float f16v;

#define T_TOT 8
#define NSP 32768   // T*H*W
#define K_TOT 1024
#define M_TOT 1024

__device__ __forceinline__ unsigned short f2bf(float f) {
  unsigned int u = __float_as_uint(f);
  u += 0x7FFF + ((u >> 16) & 1);   // round-to-nearest-even
  return (unsigned short)(u >> 16);
}

// ---------------------------------------------------------------------------
// Kernel 1 (unchanged, ~35us, at its BW floor): depthwise 3x3x3.
// ---------------------------------------------------------------------------
__global__ __launch_bounds__(256) void dw_kernel(const float* __restrict__ X,
                                                 const float* __restrict__ DW,
                                                 unsigned short* __restrict__ Yn) {
  __shared__ float xin[8 * 18 * 64];         // 36 KB  [t][hr][w]
  const int tid = threadIdx.x;
  const int hb  = blockIdx.x;                // 0..3
  const int c   = blockIdx.y;                // 0..1023
  const int h0  = hb * 16;

  float kw[27];
#pragma unroll
  for (int j = 0; j < 27; ++j) kw[j] = DW[j];

  const float* Xc = X + (size_t)c * NSP;

#pragma unroll
  for (int i = 0; i < 9; ++i) {
    const int f  = tid + i * 256;
    const int r  = f >> 4;
    const int wq = (f & 15) * 4;
    const int t  = r / 18;
    const int hr = r - t * 18;
    const int hg = h0 - 1 + hr;
    const int hc = min(max(hg, 0), 63);
    float4 v = *(const float4*)(Xc + (t * 64 + hc) * 64 + wq);
    if (hg != hc) v = (float4){0.f, 0.f, 0.f, 0.f};
    *(float4*)&xin[r * 64 + wq] = v;
  }
  __syncthreads();

  const int w  = tid & 63;
  const int hq = tid >> 6;
  const int wl = (w == 0)  ? w : w - 1;
  const int wr = (w == 63) ? w : w + 1;
  const float* bC = &xin[(hq * 4) * 64 + w];
  const float* bL = &xin[(hq * 4) * 64 + wl];
  const float* bR = &xin[(hq * 4) * 64 + wr];
  unsigned short* Yb = Yn + (size_t)c * NSP + (h0 + hq * 4) * 64 + w;

  float a0[4], a1[4], a2[4];
#pragma unroll
  for (int j = 0; j < 4; ++j) { a0[j] = 0.f; a1[j] = 0.f; a2[j] = 0.f; }

#pragma unroll
  for (int tp = 0; tp < 8; ++tp) {
    float v[6][3];
#pragma unroll
    for (int rr = 0; rr < 6; ++rr) {
      const int off = (tp * 18 + rr) * 64;
      float xc = bC[off];
      float xl = bL[off];
      float xr = bR[off];
      if (w == 0)  xl = 0.f;
      if (w == 63) xr = 0.f;
      v[rr][0] = xl; v[rr][1] = xc; v[rr][2] = xr;
    }
#pragma unroll
    for (int j = 0; j < 4; ++j)
#pragma unroll
      for (int kh = 0; kh < 3; ++kh)
#pragma unroll
        for (int kd = 0; kd < 3; ++kd) {
          const float xv = v[j + kh][kd];
          if (tp >= 1) a0[j] += kw[(2 * 3 + kh) * 3 + kd] * xv;
          a1[j] += kw[(1 * 3 + kh) * 3 + kd] * xv;
          if (tp <= 6) a2[j] += kw[(0 * 3 + kh) * 3 + kd] * xv;
        }
    if (tp >= 1) {
      unsigned short* yp = Yb + (size_t)(tp - 1) * 4096;
#pragma unroll
      for (int j = 0; j < 4; ++j) yp[j * 64] = f2bf(a0[j]);
    }
#pragma unroll
    for (int j = 0; j < 4; ++j) { a0[j] = a1[j]; a1[j] = a2[j]; a2[j] = 0.f; }
  }
  {
    unsigned short* yp = Yb + (size_t)7 * 4096;
#pragma unroll
    for (int j = 0; j < 4; ++j) yp[j * 64] = f2bf(a0[j]);
  }
}

// ---------------------------------------------------------------------------
// Kernel 1b (unchanged, ~21us, at BW floor): transpose Yn[c][n] -> Yt[n][c].
// ---------------------------------------------------------------------------
__global__ __launch_bounds__(256) void tr_kernel(const unsigned short* __restrict__ Yn,
                                                 unsigned short* __restrict__ Yt) {
  __shared__ unsigned short tb[64][68];
  const int tid = threadIdx.x;
  const int n0  = blockIdx.x * 64;
  const int c0  = blockIdx.y * 64;

#pragma unroll
  for (int i = 0; i < 2; ++i) {
    const int cl = (tid >> 3) + i * 32;
    const int n8 = (tid & 7) * 8;
    const uint4 v = *(const uint4*)(Yn + (size_t)(c0 + cl) * NSP + n0 + n8);
    uint2 lo; lo.x = v.x; lo.y = v.y;
    uint2 hi; hi.x = v.z; hi.y = v.w;
    *(uint2*)&tb[cl][n8]     = lo;
    *(uint2*)&tb[cl][n8 + 4] = hi;
  }
  __syncthreads();

  const int nl = tid >> 2;
  const int cq = tid & 3;
#pragma unroll
  for (int i = 0; i < 2; ++i) {
    const int c8 = cq * 8 + i * 32;
    unsigned int p[4];
#pragma unroll
    for (int j = 0; j < 4; ++j) {
      const unsigned int a = tb[c8 + 2 * j][nl];
      const unsigned int b = tb[c8 + 2 * j + 1][nl];
      p[j] = a | (b << 16);
    }
    uint4 o; o.x = p[0]; o.y = p[1]; o.z = p[2]; o.w = p[3];
    *(uint4*)(Yt + (size_t)(n0 + nl) * 1024 + c0 + c8) = o;
  }
}

// ---------------------------------------------------------------------------
// Kernel 2: pointwise weight fp32 -> bf16
// ---------------------------------------------------------------------------
__global__ __launch_bounds__(256) void castw_kernel(const float* __restrict__ Wf,
                                                    unsigned short* __restrict__ Wb) {
  const int i = (blockIdx.x * 256 + threadIdx.x) * 4;
  float4 v = *(const float4*)&Wf[i];
  ushort4 o;
  o.x = f2bf(v.x); o.y = f2bf(v.y); o.z = f2bf(v.z); o.w = f2bf(v.w);
  *(ushort4*)&Wb[i] = o;
}

// ---------------------------------------------------------------------------
// Kernel 3 (v9 = round-9 v6 skeleton + 32x32x16 MFMA): C = A[M][K]*Bt[N][K]^T.
// BM=BN=256, BK=64, 512 thr (8 waves 2Mx4N), wave-tile 128x64.
// Fragments: 4m x 2n of 32x32, acc f16v (16 f32) each = 128 f32/thread.
// A-frag: row = lane&31, k = (lane>>5)*8+j (2-group analog of the verified
// 16x16 mapping).  C/D: col = lane&31, row = (reg&3)+8*(reg>>2)+4*(lane>>5)
// [HW-verified m74/m101].
// LDS 128KB = 2 buf x {Akk0,Akk1,Bkk0,Bkk1} x 16KB [256][32], proven
// both-sides XOR swizzle; read col for k-step ks:
//   cph32[ks] = ((ks*2 + (lane>>5)) ^ ((lane>>1)&3)) * 8
// (row-XOR term = lane bits 1-2, identical for 32-row frags).
// Schedule (v6, equal-best measured): 2 phases/K-tile, stage t+1.kk inside
// P(t,kk), every boundary vmcnt(4)+s_barrier (counted, never drains in
// steady state), vmcnt(0) once before the tail tile.
// ---------------------------------------------------------------------------
__device__ __forceinline__ void gload_lds16(const void* g, void* lds) {
  __builtin_amdgcn_global_load_lds(
      (const __attribute__((address_space(1))) void*)(uintptr_t)g,
      (__attribute__((address_space(3))) void*)(uintptr_t)lds, 16, 0, 0);
}

__global__ __launch_bounds__(512, 2) void gemm8_kernel(const unsigned short* __restrict__ A,
                                                       const unsigned short* __restrict__ B,
                                                       float* __restrict__ C) {
  __shared__ char smem[131072];              // 2 x {A0,A1,B0,B1} x 16KB
  const int tid  = threadIdx.x;
  const int lane = tid & 63;
  const int wid  = tid >> 6;
  const int wm   = wid >> 2, wn = wid & 3;   // 2 x 4 wave grid

  // bijective XCD remap: 512 wgs, 64 per XCD; bm fastest.
  const int wg = (int)blockIdx.x;
  const int lg = (wg & 7) * 64 + (wg >> 3);
  const int bm = lg & 3;                     // 0..3   (M/256)
  const int bn = lg >> 2;                    // 0..127 (N/256)

  f16v acc[4][2];
#pragma unroll
  for (int i = 0; i < 4; ++i)
#pragma unroll
    for (int j = 0; j < 2; ++j)
#pragma unroll
      for (int e = 0; e < 16; ++e) acc[i][j][e] = 0.f;

  const int r  = tid >> 2;                                   // 0..127
  const int kb = (((tid & 3) ^ ((tid >> 3) & 3)) * 8);       // pre-swizzled k
  const unsigned short* ga = A + (size_t)(bm * 256 + r) * K_TOT + kb;
  const unsigned short* gb = B + (size_t)(bn * 256 + r) * K_TOT + kb;
  const int stg = wid * 1024;

  // stage one kk-half of tile tt into buffer nb: A region + B region, 4 loads
#define STAGE_KK(nb, tt, kk)                                                  \
  do {                                                                        \
    const int ko = (tt) * 64 + (kk) * 32;                                     \
    char* ab = smem + (nb) + (kk) * 16384 + stg;                              \
    char* bb = smem + (nb) + 32768 + (kk) * 16384 + stg;                      \
    gload_lds16(ga + ko,                 ab);                                 \
    gload_lds16(ga + 128 * K_TOT + ko,   ab + 8192);                          \
    gload_lds16(gb + ko,                 bb);                                 \
    gload_lds16(gb + 128 * K_TOT + ko,   bb + 8192);                          \
  } while (0)

  // swizzled read cols for the two k-steps (16 k each) within a 32k region
  const int xorr  = (lane >> 1) & 3;
  const int khalf = lane >> 5;               // 0 or 1
  const int cph0  = (((0 * 2) + khalf) ^ xorr) * 8;
  const int cph1  = (((1 * 2) + khalf) ^ xorr) * 8;
  const int arow  = wm * 128 + (lane & 31);
  const int brow  = wn * 64  + (lane & 31);

  // one phase: read kk regions of buffer cu, optionally stage t+1's kk half
  // into nx, then 16 MFMAs (32x32x16) for this kk.
#define PHASE(cu, nx, tt, kk, pf)                                             \
  do {                                                                        \
    const unsigned short* Ac = (const unsigned short*)(smem + (cu) + (kk) * 16384); \
    const unsigned short* Bc = (const unsigned short*)(smem + (cu) + 32768 + (kk) * 16384); \
    s8v av[4][2], bv[2][2];                                                   \
    _Pragma("unroll")                                                         \
    for (int nf = 0; nf < 2; ++nf) {                                          \
      bv[nf][0] = *(const s8v*)&Bc[(brow + nf * 32) * 32 + cph0];             \
      bv[nf][1] = *(const s8v*)&Bc[(brow + nf * 32) * 32 + cph1];             \
    }                                                                         \
    _Pragma("unroll")                                                         \
    for (int mf = 0; mf < 4; ++mf) {                                          \
      av[mf][0] = *(const s8v*)&Ac[(arow + mf * 32) * 32 + cph0];             \
      av[mf][1] = *(const s8v*)&Ac[(arow + mf * 32) * 32 + cph1];             \
    }                                                                         \
    if (pf) STAGE_KK(nx, (tt) + 1, kk);                                       \
    __builtin_amdgcn_s_setprio(1);                                            \
    _Pragma("unroll")                                                         \
    for (int mf = 0; mf < 4; ++mf)                                            \
      _Pragma("unroll")                                                       \
      for (int nf = 0; nf < 2; ++nf) {                                        \
        acc[mf][nf] = __builtin_amdgcn_mfma_f32_32x32x16_bf16(                \
            av[mf][0], bv[nf][0], acc[mf][nf], 0, 0, 0);                      \
        acc[mf][nf] = __builtin_amdgcn_mfma_f32_32x32x16_bf16(                \
            av[mf][1], bv[nf][1], acc[mf][nf], 0, 0, 0);                      \
      }                                                                       \
    __builtin_amdgcn_s_setprio(0);                                            \
  } while (0)

  // prologue: tile 0 both halves in flight (8 loads)
  STAGE_KK(0, 0, 0);
  STAGE_KK(0, 0, 1);

  for (int t = 0; t < 15; ++t) {
    const int cu = (t & 1) << 16;
    const int nx = cu ^ 65536;
    asm volatile("s_waitcnt vmcnt(4)" ::: "memory");   // t.kk0 landed; t.kk1 may fly
    __builtin_amdgcn_s_barrier();
    PHASE(cu, nx, t, 0, true);                         // issues t+1.kk0
    asm volatile("s_waitcnt vmcnt(4)" ::: "memory");   // t.kk1 landed; t+1.kk0 may fly
    __builtin_amdgcn_s_barrier();
    PHASE(cu, nx, t, 1, true);                         // issues t+1.kk1
  }
  // tail: tile 15 (buffer 1), nothing left to prefetch
  asm volatile("s_waitcnt vmcnt(0)" ::: "memory");
  __builtin_amdgcn_s_barrier();
  PHASE(65536, 0, 15, 0, false);
  PHASE(65536, 0, 15, 1, false);

#undef PHASE
#undef STAGE_KK

  // epilogue: 32x32 C/D layout col=lane&31, row=(reg&3)+8*(reg>>2)+4*(lane>>5)
  const int colq = lane & 31;
  const int rhi  = 4 * (lane >> 5);
#pragma unroll
  for (int mf = 0; mf < 4; ++mf) {
    const int row0 = bm * 256 + wm * 128 + mf * 32 + rhi;
#pragma unroll
    for (int nf = 0; nf < 2; ++nf) {
      const int col = bn * 256 + wn * 64 + nf * 32 + colq;
      float* cp = C + (size_t)row0 * NSP + col;
#pragma unroll
      for (int reg = 0; reg < 16; ++reg) {
        const int rr = (reg & 3) + 8 * (reg >> 2);
        cp[(size_t)rr * NSP] = acc[mf][nf][reg];
      }
    }
  }
}

// ---------------------------------------------------------------------------
// Fallback GEMM (round-3 verbatim): used only if ws can't fit Yn+Yt.
// ---------------------------------------------------------------------------
__global__ __launch_bounds__(256) void gemm_nmajor_kernel(const unsigned short* __restrict__ A,
                                                          const unsigned short* __restrict__ B,
                                                          float* __restrict__ C) {
  __shared__ unsigned short As[128][32];
  __shared__ unsigned short Bs[128][40];
  const int tid  = threadIdx.x;
  const int lane = tid & 63;
  const int wv   = tid >> 6;
  const int wr   = wv >> 1, wc = wv & 1;
  const int bn   = blockIdx.x, bm = blockIdx.y;
  const int n0   = bn * 128;

  f4v acc[4][4];
#pragma unroll
  for (int i = 0; i < 4; ++i)
#pragma unroll
    for (int j = 0; j < 4; ++j) acc[i][j] = (f4v){0.f, 0.f, 0.f, 0.f};

  const int r  = tid >> 2;
  const int kb = (tid & 3) * 8;
  const unsigned short* ga0 = A + (size_t)(bm * 128 + r) * K_TOT + kb;
  char* ldsA = (char*)(&As[0][0]) + wv * 1024;
  const int nq4 = (tid >> 3) * 4;
  const int kq4 = (tid & 7) * 4;

  for (int kt = 0; kt < K_TOT; kt += 32) {
    __syncthreads();
    gload_lds16(ga0 + kt,               ldsA);
    gload_lds16(ga0 + 64 * K_TOT + kt,  ldsA + 4096);

    const unsigned short* gB = B + (size_t)(kt + kq4) * NSP + n0 + nq4;
    uint2 L0 = *(const uint2*)(gB);
    uint2 L1 = *(const uint2*)(gB + NSP);
    uint2 L2 = *(const uint2*)(gB + 2 * NSP);
    uint2 L3 = *(const uint2*)(gB + 3 * NSP);
    uint2 W0, W1, W2, W3;
    W0.x = (L0.x & 0xFFFFu) | (L1.x << 16);
    W0.y = (L2.x & 0xFFFFu) | (L3.x << 16);
    W1.x = (L0.x >> 16) | (L1.x & 0xFFFF0000u);
    W1.y = (L2.x >> 16) | (L3.x & 0xFFFF0000u);
    W2.x = (L0.y & 0xFFFFu) | (L1.y << 16);
    W2.y = (L2.y & 0xFFFFu) | (L3.y << 16);
    W3.x = (L0.y >> 16) | (L1.y & 0xFFFF0000u);
    W3.y = (L2.y >> 16) | (L3.y & 0xFFFF0000u);
    *(uint2*)&Bs[nq4 + 0][kq4] = W0;
    *(uint2*)&Bs[nq4 + 1][kq4] = W1;
    *(uint2*)&Bs[nq4 + 2][kq4] = W2;
    *(uint2*)&Bs[nq4 + 3][kq4] = W3;
    __syncthreads();

    s8v a[4], b[4];
#pragma unroll
    for (int mf = 0; mf < 4; ++mf)
      a[mf] = *(const s8v*)&As[wr * 64 + mf * 16 + (lane & 15)][(lane >> 4) * 8];
#pragma unroll
    for (int nf = 0; nf < 4; ++nf)
      b[nf] = *(const s8v*)&Bs[wc * 64 + nf * 16 + (lane & 15)][(lane >> 4) * 8];
#pragma unroll
    for (int mf = 0; mf < 4; ++mf)
#pragma unroll
      for (int nf = 0; nf < 4; ++nf)
        acc[mf][nf] = __builtin_amdgcn_mfma_f32_16x16x32_bf16(a[mf], b[nf], acc[mf][nf], 0, 0, 0);
  }

  const int rowq = (lane >> 4) * 4;
  const int colq = lane & 15;
#pragma unroll
  for (int mf = 0; mf < 4; ++mf) {
    const int row0 = bm * 128 + wr * 64 + mf * 16 + rowq;
#pragma unroll
    for (int nf = 0; nf < 4; ++nf) {
      const int col = n0 + wc * 64 + nf * 16 + colq;
      float* cp = C + (size_t)row0 * NSP + col;
#pragma unroll
      for (int j = 0; j < 4; ++j) cp[(size_t)j * NSP] = acc[mf][nf][j];
    }
  }
}

// ---------------------------------------------------------------------------
extern "C" void kernel_launch(void* const* d_in, const int* in_sizes, int n_in,
                              void* d_out, int out_size, void* d_ws, size_t ws_size,
                              hipStream_t stream) {
  const float* feat = (const float*)d_in[0];
  const float* dw   = (const float*)d_in[1];
  const float* pw   = (const float*)d_in[2];
  float* out = (float*)d_out;

  const size_t YBYTES = (size_t)K_TOT * NSP * 2;   // 64 MiB

  if (ws_size >= 2 * YBYTES) {
    unsigned short* Yt = (unsigned short*)d_ws;
    unsigned short* Yn = (unsigned short*)((char*)d_ws + YBYTES);
    unsigned short* Wb = Yn;                       // reused after tr_kernel
    dw_kernel<<<dim3(4, 1024), dim3(256), 0, stream>>>(feat, dw, Yn);
    tr_kernel<<<dim3(512, 16), dim3(256), 0, stream>>>(Yn, Yt);
    castw_kernel<<<dim3(1024), dim3(256), 0, stream>>>(pw, Wb);
    gemm8_kernel<<<dim3(512), dim3(512), 0, stream>>>(Wb, Yt, out);
  } else {
    unsigned short* Yn = (unsigned short*)d_ws;
    unsigned short* Wb = Yn + (size_t)K_TOT * NSP;
    dw_kernel<<<dim3(4, 1024), dim3(256), 0, stream>>>(feat, dw, Yn);
    castw_kernel<<<dim3(1024), dim3(256), 0, stream>>>(pw, Wb);
    gemm_nmajor_kernel<<<dim3(256, 8), dim3(256), 0, stream>>>(Wb, Yn, out);
  }
}

// Round 15
// 158.430 us; speedup vs baseline: 1.0903x; 1.0039x over previous
//
#include <hip/hip_runtime.h>
#include <hip/hip_bf16.h>
#include <stdint.h>

typedef __attribute__((ext_vector_type(8))) short s8v;
typedef __attribute__((ext_vector_type(4))) float f4v;

#define T_TOT 8
#define NSP 32768   // T*H*W
#define K_TOT 1024
#define M_TOT 1024

__device__ __forceinline__ unsigned short f2bf(float f) {
  unsigned int u = __float_as_uint(f);
  u += 0x7FFF + ((u >> 16) & 1);   // round-to-nearest-even
  return (unsigned short)(u >> 16);
}

// ---------------------------------------------------------------------------
// Kernel 1 (+castw fold): depthwise 3x3x3 (~35us, BW floor).  Blocks with
// bx==4 cast the pointwise weight fp32->bf16 (rides in dw's shadow).
// ---------------------------------------------------------------------------
__global__ __launch_bounds__(256) void dw_kernel(const float* __restrict__ X,
                                                 const float* __restrict__ DW,
                                                 unsigned short* __restrict__ Yn,
                                                 const float* __restrict__ Wf,
                                                 unsigned short* __restrict__ Wb) {
  if (blockIdx.x == 4) {                     // castw branch: 1024 elems/block
    const int i = (blockIdx.y * 256 + threadIdx.x) * 4;
    float4 v = *(const float4*)&Wf[i];
    ushort4 o;
    o.x = f2bf(v.x); o.y = f2bf(v.y); o.z = f2bf(v.z); o.w = f2bf(v.w);
    *(ushort4*)&Wb[i] = o;
    return;
  }

  __shared__ float xin[8 * 18 * 64];         // 36 KB  [t][hr][w]
  const int tid = threadIdx.x;
  const int hb  = blockIdx.x;                // 0..3
  const int c   = blockIdx.y;                // 0..1023
  const int h0  = hb * 16;

  float kw[27];
#pragma unroll
  for (int j = 0; j < 27; ++j) kw[j] = DW[j];

  const float* Xc = X + (size_t)c * NSP;

#pragma unroll
  for (int i = 0; i < 9; ++i) {
    const int f  = tid + i * 256;
    const int r  = f >> 4;
    const int wq = (f & 15) * 4;
    const int t  = r / 18;
    const int hr = r - t * 18;
    const int hg = h0 - 1 + hr;
    const int hc = min(max(hg, 0), 63);
    float4 v = *(const float4*)(Xc + (t * 64 + hc) * 64 + wq);
    if (hg != hc) v = (float4){0.f, 0.f, 0.f, 0.f};
    *(float4*)&xin[r * 64 + wq] = v;
  }
  __syncthreads();

  const int w  = tid & 63;
  const int hq = tid >> 6;
  const int wl = (w == 0)  ? w : w - 1;
  const int wr = (w == 63) ? w : w + 1;
  const float* bC = &xin[(hq * 4) * 64 + w];
  const float* bL = &xin[(hq * 4) * 64 + wl];
  const float* bR = &xin[(hq * 4) * 64 + wr];
  unsigned short* Yb = Yn + (size_t)c * NSP + (h0 + hq * 4) * 64 + w;

  float a0[4], a1[4], a2[4];
#pragma unroll
  for (int j = 0; j < 4; ++j) { a0[j] = 0.f; a1[j] = 0.f; a2[j] = 0.f; }

#pragma unroll
  for (int tp = 0; tp < 8; ++tp) {
    float v[6][3];
#pragma unroll
    for (int rr = 0; rr < 6; ++rr) {
      const int off = (tp * 18 + rr) * 64;
      float xc = bC[off];
      float xl = bL[off];
      float xr = bR[off];
      if (w == 0)  xl = 0.f;
      if (w == 63) xr = 0.f;
      v[rr][0] = xl; v[rr][1] = xc; v[rr][2] = xr;
    }
#pragma unroll
    for (int j = 0; j < 4; ++j)
#pragma unroll
      for (int kh = 0; kh < 3; ++kh)
#pragma unroll
        for (int kd = 0; kd < 3; ++kd) {
          const float xv = v[j + kh][kd];
          if (tp >= 1) a0[j] += kw[(2 * 3 + kh) * 3 + kd] * xv;
          a1[j] += kw[(1 * 3 + kh) * 3 + kd] * xv;
          if (tp <= 6) a2[j] += kw[(0 * 3 + kh) * 3 + kd] * xv;
        }
    if (tp >= 1) {
      unsigned short* yp = Yb + (size_t)(tp - 1) * 4096;
#pragma unroll
      for (int j = 0; j < 4; ++j) yp[j * 64] = f2bf(a0[j]);
    }
#pragma unroll
    for (int j = 0; j < 4; ++j) { a0[j] = a1[j]; a1[j] = a2[j]; a2[j] = 0.f; }
  }
  {
    unsigned short* yp = Yb + (size_t)7 * 4096;
#pragma unroll
    for (int j = 0; j < 4; ++j) yp[j * 64] = f2bf(a0[j]);
  }
}

// ---------------------------------------------------------------------------
// Kernel 1b (unchanged, ~21us, BW floor): transpose Yn[c][n] -> Yt[n][c].
// ---------------------------------------------------------------------------
__global__ __launch_bounds__(256) void tr_kernel(const unsigned short* __restrict__ Yn,
                                                 unsigned short* __restrict__ Yt) {
  __shared__ unsigned short tb[64][68];
  const int tid = threadIdx.x;
  const int n0  = blockIdx.x * 64;
  const int c0  = blockIdx.y * 64;

#pragma unroll
  for (int i = 0; i < 2; ++i) {
    const int cl = (tid >> 3) + i * 32;
    const int n8 = (tid & 7) * 8;
    const uint4 v = *(const uint4*)(Yn + (size_t)(c0 + cl) * NSP + n0 + n8);
    uint2 lo; lo.x = v.x; lo.y = v.y;
    uint2 hi; hi.x = v.z; hi.y = v.w;
    *(uint2*)&tb[cl][n8]     = lo;
    *(uint2*)&tb[cl][n8 + 4] = hi;
  }
  __syncthreads();

  const int nl = tid >> 2;
  const int cq = tid & 3;
#pragma unroll
  for (int i = 0; i < 2; ++i) {
    const int c8 = cq * 8 + i * 32;
    unsigned int p[4];
#pragma unroll
    for (int j = 0; j < 4; ++j) {
      const unsigned int a = tb[c8 + 2 * j][nl];
      const unsigned int b = tb[c8 + 2 * j + 1][nl];
      p[j] = a | (b << 16);
    }
    uint4 o; o.x = p[0]; o.y = p[1]; o.z = p[2]; o.w = p[3];
    *(uint4*)(Yt + (size_t)(n0 + nl) * 1024 + c0 + c8) = o;
  }
}

// ---------------------------------------------------------------------------
// Kernel 3 (v10b = v10 with the K-coverage FIX: 32 tiles of BK=32, not 16):
// C = A[M][K]*Bt[N][K]^T.  1024 threads, 16 waves (4x4), wave-tile 64x64,
// acc[4][4]=64 f32 -> ~115 VGPR, __launch_bounds__(1024,4) = 4 waves/SIMD
// (2x every previous variant).  LDS 64KB = 2 buf x {A[256][32], B[256][32]},
// proven both-sides XOR swizzle.  Staging: 1 gload_lds/thread/region.
// Phase: STAGE(t+1) first -> 8 ds_read_b128 -> 16 MFMA -> vmcnt(0)+barrier
// (load issued a full compute phase earlier; TLP experiment).
// ---------------------------------------------------------------------------
__device__ __forceinline__ void gload_lds16(const void* g, void* lds) {
  __builtin_amdgcn_global_load_lds(
      (const __attribute__((address_space(1))) void*)(uintptr_t)g,
      (__attribute__((address_space(3))) void*)(uintptr_t)lds, 16, 0, 0);
}

__global__ __launch_bounds__(1024, 4) void gemm10_kernel(const unsigned short* __restrict__ A,
                                                         const unsigned short* __restrict__ B,
                                                         float* __restrict__ C) {
  __shared__ char smem[65536];               // 2 x {A 16KB, B 16KB}
  const int tid  = threadIdx.x;
  const int lane = tid & 63;
  const int wid  = tid >> 6;                 // 0..15
  const int wm   = wid >> 2, wn = wid & 3;   // 4 x 4 wave grid

  // bijective XCD remap: 512 wgs, 64 per XCD; bm fastest.
  const int wg = (int)blockIdx.x;
  const int lg = (wg & 7) * 64 + (wg >> 3);
  const int bm = lg & 3;                     // 0..3   (M/256)
  const int bn = lg >> 2;                    // 0..127 (N/256)

  f4v acc[4][4];
#pragma unroll
  for (int i = 0; i < 4; ++i)
#pragma unroll
    for (int j = 0; j < 4; ++j) acc[i][j] = (f4v){0.f, 0.f, 0.f, 0.f};

  const int row = tid >> 2;                                  // 0..255
  const int kb  = (((tid & 3) ^ ((tid >> 3) & 3)) * 8);      // pre-swizzled k
  const unsigned short* ga = A + (size_t)(bm * 256 + row) * K_TOT + kb;
  const unsigned short* gb = B + (size_t)(bn * 256 + row) * K_TOT + kb;
  const int stg = wid * 1024;                // wave-uniform LDS base offset

#define STAGE(nb, tt)                                                         \
  do {                                                                        \
    gload_lds16(ga + (tt) * 32, smem + (nb) + stg);                           \
    gload_lds16(gb + (tt) * 32, smem + (nb) + 16384 + stg);                   \
  } while (0)

  const int cph  = ((lane >> 4) ^ ((lane >> 1) & 3)) * 8;    // swizzled col
  const int arow = wm * 64 + (lane & 15);
  const int brow = wn * 64 + (lane & 15);

  // prologue: tile 0 into buffer 0
  STAGE(0, 0);
  asm volatile("s_waitcnt vmcnt(0)" ::: "memory");
  __builtin_amdgcn_s_barrier();

#pragma unroll 2
  for (int t = 0; t < 32; ++t) {             // 32 tiles x BK=32 = K_TOT
    const int cu = (t & 1) << 15;            // 0 / 32768
    const int nx = cu ^ 32768;
    if (t < 31) STAGE(nx, t + 1);            // issue first: full phase to land
    const unsigned short* Ac = (const unsigned short*)(smem + cu);
    const unsigned short* Bc = (const unsigned short*)(smem + cu + 16384);
    s8v av[4], bv[4];
#pragma unroll
    for (int nf = 0; nf < 4; ++nf)
      bv[nf] = *(const s8v*)&Bc[(brow + nf * 16) * 32 + cph];
#pragma unroll
    for (int mf = 0; mf < 4; ++mf)
      av[mf] = *(const s8v*)&Ac[(arow + mf * 16) * 32 + cph];
    __builtin_amdgcn_s_setprio(1);
#pragma unroll
    for (int mf = 0; mf < 4; ++mf)
#pragma unroll
      for (int nf = 0; nf < 4; ++nf)
        acc[mf][nf] = __builtin_amdgcn_mfma_f32_16x16x32_bf16(av[mf], bv[nf], acc[mf][nf], 0, 0, 0);
    __builtin_amdgcn_s_setprio(0);
    if (t < 31) {
      asm volatile("s_waitcnt vmcnt(0)" ::: "memory");
      __builtin_amdgcn_s_barrier();
    }
  }
#undef STAGE

  const int rowq = (lane >> 4) * 4;
  const int colq = lane & 15;
#pragma unroll
  for (int mf = 0; mf < 4; ++mf) {
    const int row0 = bm * 256 + wm * 64 + mf * 16 + rowq;
#pragma unroll
    for (int nf = 0; nf < 4; ++nf) {
      const int col = bn * 256 + wn * 64 + nf * 16 + colq;
      float* cp = C + (size_t)row0 * NSP + col;
#pragma unroll
      for (int j = 0; j < 4; ++j) cp[(size_t)j * NSP] = acc[mf][nf][j];
    }
  }
}

// ---------------------------------------------------------------------------
// Fallback GEMM (round-3 verbatim): used only if ws can't fit Yn+Yt+Wb.
// ---------------------------------------------------------------------------
__global__ __launch_bounds__(256) void gemm_nmajor_kernel(const unsigned short* __restrict__ A,
                                                          const unsigned short* __restrict__ B,
                                                          float* __restrict__ C) {
  __shared__ unsigned short As[128][32];
  __shared__ unsigned short Bs[128][40];
  const int tid  = threadIdx.x;
  const int lane = tid & 63;
  const int wv   = tid >> 6;
  const int wr   = wv >> 1, wc = wv & 1;
  const int bn   = blockIdx.x, bm = blockIdx.y;
  const int n0   = bn * 128;

  f4v acc[4][4];
#pragma unroll
  for (int i = 0; i < 4; ++i)
#pragma unroll
    for (int j = 0; j < 4; ++j) acc[i][j] = (f4v){0.f, 0.f, 0.f, 0.f};

  const int r  = tid >> 2;
  const int kb = (tid & 3) * 8;
  const unsigned short* ga0 = A + (size_t)(bm * 128 + r) * K_TOT + kb;
  char* ldsA = (char*)(&As[0][0]) + wv * 1024;
  const int nq4 = (tid >> 3) * 4;
  const int kq4 = (tid & 7) * 4;

  for (int kt = 0; kt < K_TOT; kt += 32) {
    __syncthreads();
    gload_lds16(ga0 + kt,               ldsA);
    gload_lds16(ga0 + 64 * K_TOT + kt,  ldsA + 4096);

    const unsigned short* gB = B + (size_t)(kt + kq4) * NSP + n0 + nq4;
    uint2 L0 = *(const uint2*)(gB);
    uint2 L1 = *(const uint2*)(gB + NSP);
    uint2 L2 = *(const uint2*)(gB + 2 * NSP);
    uint2 L3 = *(const uint2*)(gB + 3 * NSP);
    uint2 W0, W1, W2, W3;
    W0.x = (L0.x & 0xFFFFu) | (L1.x << 16);
    W0.y = (L2.x & 0xFFFFu) | (L3.x << 16);
    W1.x = (L0.x >> 16) | (L1.x & 0xFFFF0000u);
    W1.y = (L2.x >> 16) | (L3.x & 0xFFFF0000u);
    W2.x = (L0.y & 0xFFFFu) | (L1.y << 16);
    W2.y = (L2.y & 0xFFFFu) | (L3.y << 16);
    W3.x = (L0.y >> 16) | (L1.y & 0xFFFF0000u);
    W3.y = (L2.y >> 16) | (L3.y & 0xFFFF0000u);
    *(uint2*)&Bs[nq4 + 0][kq4] = W0;
    *(uint2*)&Bs[nq4 + 1][kq4] = W1;
    *(uint2*)&Bs[nq4 + 2][kq4] = W2;
    *(uint2*)&Bs[nq4 + 3][kq4] = W3;
    __syncthreads();

    s8v a[4], b[4];
#pragma unroll
    for (int mf = 0; mf < 4; ++mf)
      a[mf] = *(const s8v*)&As[wr * 64 + mf * 16 + (lane & 15)][(lane >> 4) * 8];
#pragma unroll
    for (int nf = 0; nf < 4; ++nf)
      b[nf] = *(const s8v*)&Bs[wc * 64 + nf * 16 + (lane & 15)][(lane >> 4) * 8];
#pragma unroll
    for (int mf = 0; mf < 4; ++mf)
#pragma unroll
      for (int nf = 0; nf < 4; ++nf)
        acc[mf][nf] = __builtin_amdgcn_mfma_f32_16x16x32_bf16(a[mf], b[nf], acc[mf][nf], 0, 0, 0);
  }

  const int rowq = (lane >> 4) * 4;
  const int colq = lane & 15;
#pragma unroll
  for (int mf = 0; mf < 4; ++mf) {
    const int row0 = bm * 128 + wr * 64 + mf * 16 + rowq;
#pragma unroll
    for (int nf = 0; nf < 4; ++nf) {
      const int col = n0 + wc * 64 + nf * 16 + colq;
      float* cp = C + (size_t)row0 * NSP + col;
#pragma unroll
      for (int j = 0; j < 4; ++j) cp[(size_t)j * NSP] = acc[mf][nf][j];
    }
  }
}

// ---------------------------------------------------------------------------
extern "C" void kernel_launch(void* const* d_in, const int* in_sizes, int n_in,
                              void* d_out, int out_size, void* d_ws, size_t ws_size,
                              hipStream_t stream) {
  const float* feat = (const float*)d_in[0];
  const float* dw   = (const float*)d_in[1];
  const float* pw   = (const float*)d_in[2];
  float* out = (float*)d_out;

  const size_t YBYTES = (size_t)K_TOT * NSP * 2;   // 64 MiB
  const size_t WBYTES = (size_t)M_TOT * K_TOT * 2; // 2 MiB

  if (ws_size >= 2 * YBYTES + WBYTES) {
    // main path (needs 130 MiB; confirmed available — round-14 ran this path):
    // Yt@0, Yn@64MiB, Wb@128MiB (castw fused into dw runs BEFORE tr, so Wb
    // must not overlap Yn/Yt).
    unsigned short* Yt = (unsigned short*)d_ws;
    unsigned short* Yn = (unsigned short*)((char*)d_ws + YBYTES);
    unsigned short* Wb = (unsigned short*)((char*)d_ws + 2 * YBYTES);
    dw_kernel<<<dim3(5, 1024), dim3(256), 0, stream>>>(feat, dw, Yn, pw, Wb);
    tr_kernel<<<dim3(512, 16), dim3(256), 0, stream>>>(Yn, Yt);
    gemm10_kernel<<<dim3(512), dim3(1024), 0, stream>>>(Wb, Yt, out);
  } else {
    // fallback (66 MiB, proven round-3 path): Yn@0, Wb@64MiB
    unsigned short* Yn = (unsigned short*)d_ws;
    unsigned short* Wb = Yn + (size_t)K_TOT * NSP;
    dw_kernel<<<dim3(5, 1024), dim3(256), 0, stream>>>(feat, dw, Yn, pw, Wb);
    gemm_nmajor_kernel<<<dim3(256, 8), dim3(256), 0, stream>>>(Wb, Yn, out);
  }
}

// Round 16
// 149.820 us; speedup vs baseline: 1.1530x; 1.0575x over previous
//
#include <hip/hip_runtime.h>
#include <hip/hip_bf16.h>
#include <stdint.h>

typedef __attribute__((ext_vector_type(8))) short s8v;
typedef __attribute__((ext_vector_type(4))) float f4v;

#define T_TOT 8
#define NSP 32768   // T*H*W
#define K_TOT 1024
#define M_TOT 1024

__device__ __forceinline__ unsigned short f2bf(float f) {
  unsigned int u = __float_as_uint(f);
  u += 0x7FFF + ((u >> 16) & 1);   // round-to-nearest-even
  return (unsigned short)(u >> 16);
}

// ---------------------------------------------------------------------------
// Kernel 1 (dw3): depthwise 3x3x3 writing k-BLOCKED output
//   Yn8[c/8][n][c%8]  (n = t*4096 + h*64 + w)
// so the GEMM can stage B with direct 16B global_load_lds (no tr_kernel).
// Block = (8 channels, h-band 16).  Per channel: stage the proven 36.9KB
// slab, compute with the proven v[6][3] ring (4.5 LDS reads/output), park
// outputs in REGISTERS (held[8][4][4] u32 = 128 VGPR, all static indices).
// Final phase: per n, write uint4 {c0..c7} -- fully coalesced 16B chunks.
// bx==4 blocks do the pointwise-weight cast (fold; saves a dispatch).
// ---------------------------------------------------------------------------
__global__ __launch_bounds__(256, 2) void dw3_kernel(const float* __restrict__ X,
                                                     const float* __restrict__ DW,
                                                     unsigned short* __restrict__ Yn8,
                                                     const float* __restrict__ Wf,
                                                     unsigned short* __restrict__ Wb) {
  if (blockIdx.x == 4) {                     // castw: 128 blocks x 8192 elems
    const int base = blockIdx.y * 8192;
#pragma unroll
    for (int it = 0; it < 8; ++it) {
      const int i = base + (it * 256 + (int)threadIdx.x) * 4;
      float4 v = *(const float4*)&Wf[i];
      ushort4 o;
      o.x = f2bf(v.x); o.y = f2bf(v.y); o.z = f2bf(v.z); o.w = f2bf(v.w);
      *(ushort4*)&Wb[i] = o;
    }
    return;
  }

  __shared__ float xin[8 * 18 * 64];         // 36.9 KB  [t][hr][w]
  const int tid = threadIdx.x;
  const int hb  = blockIdx.x;                // 0..3  (h-band of 16)
  const int cg  = blockIdx.y;                // 0..127 (channel octet)
  const int h0  = hb * 16;

  float kw[27];
#pragma unroll
  for (int j = 0; j < 27; ++j) kw[j] = DW[j];

  const int w  = tid & 63;
  const int hq = tid >> 6;
  const int wl = (w == 0)  ? w : w - 1;
  const int wr = (w == 63) ? w : w + 1;
  const float* bC = &xin[(hq * 4) * 64 + w];
  const float* bL = &xin[(hq * 4) * 64 + wl];
  const float* bR = &xin[(hq * 4) * 64 + wr];

  unsigned int held[8][4][4];                // [t][j][c>>1] packed bf16 pairs

#pragma unroll
  for (int c = 0; c < 8; ++c) {
    const float* Xc = X + (size_t)(cg * 8 + c) * NSP;

    // ---- stage slab (coalesced 1KB wave loads, h-clamped+zeroed) ----
#pragma unroll
    for (int i = 0; i < 9; ++i) {
      const int f  = tid + i * 256;
      const int r  = f >> 4;
      const int wq = (f & 15) * 4;
      const int t  = r / 18;
      const int hr = r - t * 18;
      const int hg = h0 - 1 + hr;
      const int hc = min(max(hg, 0), 63);
      float4 v = *(const float4*)(Xc + (t * 64 + hc) * 64 + wq);
      if (hg != hc) v = (float4){0.f, 0.f, 0.f, 0.f};
      *(float4*)&xin[r * 64 + wq] = v;
    }
    __syncthreads();

    // ---- compute (proven ring), outputs -> held regs ----
    float a0[4], a1[4], a2[4];
#pragma unroll
    for (int j = 0; j < 4; ++j) { a0[j] = 0.f; a1[j] = 0.f; a2[j] = 0.f; }

#pragma unroll
    for (int tp = 0; tp < 8; ++tp) {
      float v[6][3];
#pragma unroll
      for (int rr = 0; rr < 6; ++rr) {
        const int off = (tp * 18 + rr) * 64;
        float xc = bC[off];
        float xl = bL[off];
        float xr = bR[off];
        if (w == 0)  xl = 0.f;
        if (w == 63) xr = 0.f;
        v[rr][0] = xl; v[rr][1] = xc; v[rr][2] = xr;
      }
#pragma unroll
      for (int j = 0; j < 4; ++j)
#pragma unroll
        for (int kh = 0; kh < 3; ++kh)
#pragma unroll
          for (int kd = 0; kd < 3; ++kd) {
            const float xv = v[j + kh][kd];
            if (tp >= 1) a0[j] += kw[(2 * 3 + kh) * 3 + kd] * xv;
            a1[j] += kw[(1 * 3 + kh) * 3 + kd] * xv;
            if (tp <= 6) a2[j] += kw[(0 * 3 + kh) * 3 + kd] * xv;
          }
      if (tp >= 1) {
        const int to = tp - 1;
#pragma unroll
        for (int j = 0; j < 4; ++j) {
          const unsigned int b = f2bf(a0[j]);
          if (c & 1) held[to][j][c >> 1] |= (b << 16);
          else       held[to][j][c >> 1] = b;
        }
      }
#pragma unroll
      for (int j = 0; j < 4; ++j) { a0[j] = a1[j]; a1[j] = a2[j]; a2[j] = 0.f; }
    }
    {                                        // t_out = 7
#pragma unroll
      for (int j = 0; j < 4; ++j) {
        const unsigned int b = f2bf(a0[j]);
        if (c & 1) held[7][j][c >> 1] |= (b << 16);
        else       held[7][j][c >> 1] = b;
      }
    }
    __syncthreads();                         // slab reused next channel
  }

  // ---- write phase: 16B chunks {c0..c7} per n, coalesced across lanes ----
  const size_t nb = (size_t)cg * NSP;
#pragma unroll
  for (int t = 0; t < 8; ++t)
#pragma unroll
    for (int j = 0; j < 4; ++j) {
      const int n = t * 4096 + (h0 + hq * 4 + j) * 64 + w;
      uint4 o;
      o.x = held[t][j][0]; o.y = held[t][j][1];
      o.z = held[t][j][2]; o.w = held[t][j][3];
      *(uint4*)&Yn8[(nb + (size_t)n) * 8] = o;
    }
}

// ---------------------------------------------------------------------------
// Kernel 3 (v6 verbatim = round-9 best, 81us; only the B SOURCE changed):
// C = A[M][K] * Y.  BM=BN=256, BK=64, 512 thr (8 waves 2Mx4N), wave-tile
// 128x64, acc[8][4].  LDS 128KB = 2 buf x {Akk0,Akk1,Bkk0,Bkk1} x 16KB
// [256][32], proven both-sides XOR swizzle (0 conflicts).
// B stages from Yn8[octet][n][8]: row r, swizzled octet c -> one 16B
// global_load_lds, 4 dense 256B streams per wave (same pattern as A).
// Schedule: 2 phases/K-tile, stage t+1.kk inside P(t,kk), every boundary
// vmcnt(4)+s_barrier (counted; never drains in steady state), vmcnt(0)
// once before the tail tile.
// ---------------------------------------------------------------------------
__device__ __forceinline__ void gload_lds16(const void* g, void* lds) {
  __builtin_amdgcn_global_load_lds(
      (const __attribute__((address_space(1))) void*)(uintptr_t)g,
      (__attribute__((address_space(3))) void*)(uintptr_t)lds, 16, 0, 0);
}

__global__ __launch_bounds__(512, 2) void gemm8_kernel(const unsigned short* __restrict__ A,
                                                       const unsigned short* __restrict__ Yn8,
                                                       float* __restrict__ C) {
  __shared__ char smem[131072];              // 2 x {A0,A1,B0,B1} x 16KB
  const int tid  = threadIdx.x;
  const int lane = tid & 63;
  const int wid  = tid >> 6;
  const int wm   = wid >> 2, wn = wid & 3;   // 2 x 4 wave grid

  // bijective XCD remap: 512 wgs, 64 per XCD; bm fastest.
  const int wg = (int)blockIdx.x;
  const int lg = (wg & 7) * 64 + (wg >> 3);
  const int bm = lg & 3;                     // 0..3   (M/256)
  const int bn = lg >> 2;                    // 0..127 (N/256)

  f4v acc[8][4];
#pragma unroll
  for (int i = 0; i < 8; ++i)
#pragma unroll
    for (int j = 0; j < 4; ++j) acc[i][j] = (f4v){0.f, 0.f, 0.f, 0.f};

  const int r    = tid >> 2;                                 // 0..127
  const int cswz = (tid & 3) ^ ((tid >> 3) & 3);             // swizzled chunk
  const unsigned short* ga  = A + (size_t)(bm * 256 + r) * K_TOT + cswz * 8;
  // B: octet-blocked source; chunk c of a row = octet (base + cswz)
  const unsigned short* gbb = Yn8 + ((size_t)cswz * NSP + (size_t)(bn * 256 + r)) * 8;
  const int stg = wid * 1024;

  // stage one kk-half of tile tt into buffer nb: A region + B region, 4 loads
#define STAGE_KK(nb, tt, kk)                                                  \
  do {                                                                        \
    const int ko = (tt) * 64 + (kk) * 32;                                     \
    const size_t bko = (size_t)((tt) * 8 + (kk) * 4) * NSP * 8;               \
    char* ab = smem + (nb) + (kk) * 16384 + stg;                              \
    char* bb = smem + (nb) + 32768 + (kk) * 16384 + stg;                      \
    gload_lds16(ga + ko,                 ab);                                 \
    gload_lds16(ga + 128 * K_TOT + ko,   ab + 8192);                          \
    gload_lds16(gbb + bko,               bb);                                 \
    gload_lds16(gbb + bko + 128 * 8,     bb + 8192);                          \
  } while (0)

  const int cph  = ((lane >> 4) ^ ((lane >> 1) & 3)) * 8;    // swizzled col
  const int arow = wm * 128 + (lane & 15);
  const int brow = wn * 64  + (lane & 15);

#define PHASE(cu, nx, tt, kk, pf)                                             \
  do {                                                                        \
    const unsigned short* Ac = (const unsigned short*)(smem + (cu));          \
    const unsigned short* Bc = (const unsigned short*)(smem + (cu) + 32768);  \
    s8v av[8], bv[4];                                                         \
    _Pragma("unroll")                                                         \
    for (int nf = 0; nf < 4; ++nf)                                            \
      bv[nf] = *(const s8v*)&Bc[(kk) * 8192 + (brow + nf * 16) * 32 + cph];   \
    _Pragma("unroll")                                                         \
    for (int mf = 0; mf < 8; ++mf)                                            \
      av[mf] = *(const s8v*)&Ac[(kk) * 8192 + (arow + mf * 16) * 32 + cph];   \
    if (pf) STAGE_KK(nx, (tt) + 1, kk);                                       \
    __builtin_amdgcn_s_setprio(1);                                            \
    _Pragma("unroll")                                                         \
    for (int mf = 0; mf < 8; ++mf)                                            \
      _Pragma("unroll")                                                       \
      for (int nf = 0; nf < 4; ++nf)                                          \
        acc[mf][nf] = __builtin_amdgcn_mfma_f32_16x16x32_bf16(                \
            av[mf], bv[nf], acc[mf][nf], 0, 0, 0);                            \
    __builtin_amdgcn_s_setprio(0);                                            \
  } while (0)

  // prologue: tile 0 both halves in flight (8 loads)
  STAGE_KK(0, 0, 0);
  STAGE_KK(0, 0, 1);

  for (int t = 0; t < 15; ++t) {
    const int cu = (t & 1) << 16;
    const int nx = cu ^ 65536;
    asm volatile("s_waitcnt vmcnt(4)" ::: "memory");   // t.kk0 landed; t.kk1 may fly
    __builtin_amdgcn_s_barrier();
    PHASE(cu, nx, t, 0, true);                         // issues t+1.kk0
    asm volatile("s_waitcnt vmcnt(4)" ::: "memory");   // t.kk1 landed; t+1.kk0 may fly
    __builtin_amdgcn_s_barrier();
    PHASE(cu, nx, t, 1, true);                         // issues t+1.kk1
  }
  // tail: tile 15 (buffer 1), nothing left to prefetch
  asm volatile("s_waitcnt vmcnt(0)" ::: "memory");
  __builtin_amdgcn_s_barrier();
  PHASE(65536, 0, 15, 0, false);
  PHASE(65536, 0, 15, 1, false);

#undef PHASE
#undef STAGE_KK

  const int rowq = (lane >> 4) * 4;
  const int colq = lane & 15;
#pragma unroll
  for (int mf = 0; mf < 8; ++mf) {
    const int row0 = bm * 256 + wm * 128 + mf * 16 + rowq;
#pragma unroll
    for (int nf = 0; nf < 4; ++nf) {
      const int col = bn * 256 + wn * 64 + nf * 16 + colq;
      float* cp = C + (size_t)row0 * NSP + col;
#pragma unroll
      for (int j = 0; j < 4; ++j) cp[(size_t)j * NSP] = acc[mf][nf][j];
    }
  }
}

// ---------------------------------------------------------------------------
extern "C" void kernel_launch(void* const* d_in, const int* in_sizes, int n_in,
                              void* d_out, int out_size, void* d_ws, size_t ws_size,
                              hipStream_t stream) {
  const float* feat = (const float*)d_in[0];
  const float* dw   = (const float*)d_in[1];
  const float* pw   = (const float*)d_in[2];
  float* out = (float*)d_out;

  unsigned short* Yn8 = (unsigned short*)d_ws;                // [128][32768][8] bf16, 64 MiB
  unsigned short* Wb  = Yn8 + (size_t)K_TOT * NSP;            // [1024][1024] bf16, 2 MiB

  dw3_kernel<<<dim3(5, 128), dim3(256), 0, stream>>>(feat, dw, Yn8, pw, Wb);
  gemm8_kernel<<<dim3(512), dim3(512), 0, stream>>>(Wb, Yn8, out);
}